// Round 4
// baseline (8592.332 us; speedup 1.0000x reference)
//
#include <hip/hip_runtime.h>
#include <hip/hip_bf16.h>
#include <stdint.h>

#define HDIM 2048
#define BATCH 16
#define TLEN 512
#define TH   1048576        // TLEN*HDIM
#define OUT_MAIN 16777216   // BATCH*TLEN*HDIM

using floatx4 = __attribute__((ext_vector_type(4))) float;
using shortx8 = __attribute__((ext_vector_type(8))) short;
typedef unsigned long long ull;

// ---------------- cast kernels ----------------
__global__ void cast_x_kernel(const float* __restrict__ x, __hip_bfloat16* __restrict__ xb, int n) {
    int i = blockIdx.x * blockDim.x + threadIdx.x;
    int stride = gridDim.x * blockDim.x;
    for (; i < n; i += stride) xb[i] = __float2bfloat16(x[i]);
}

__global__ void cast_w_kernel(const float* __restrict__ W,
                              __hip_bfloat16* __restrict__ wxb,
                              __hip_bfloat16* __restrict__ whb) {
    int i = blockIdx.x * blockDim.x + threadIdx.x;
    int stride = gridDim.x * blockDim.x;
    for (; i < HDIM * HDIM; i += stride) {
        int g = i >> 11, k = i & (HDIM - 1);
        wxb[i] = __float2bfloat16(W[g * (2 * HDIM) + k]);
        whb[i] = __float2bfloat16(W[g * (2 * HDIM) + HDIM + k]);
    }
}

// ---------------- phase A: u = x @ Wx^T + b  -> d_out ----------------
__global__ __launch_bounds__(256) void gemm_u_kernel(
    const __hip_bfloat16* __restrict__ xb,   // [8192][2048]
    const __hip_bfloat16* __restrict__ wxb,  // [2048][2048]
    const float* __restrict__ bias,          // [2048]
    float* __restrict__ out)                 // [8192][2048]
{
    __shared__ __align__(16) __hip_bfloat16 As[4 * 128 * 8];  // 8 KB
    __shared__ __align__(16) __hip_bfloat16 Bs[4 * 128 * 8];  // 8 KB

    const int j = threadIdx.x;
    const int m0 = blockIdx.x * 128;
    const int n0 = blockIdx.y * 128;
    const int w = j >> 6, lane = j & 63;
    const int wm = (w >> 1) * 64, wn = (w & 1) * 64;
    const int quad = lane >> 4, l15 = lane & 15;

    const int mA0 = j & 127, kg0 = j >> 7;
    const int mA1 = (j + 256) & 127, kg1 = (j + 256) >> 7;

    floatx4 acc[4][4] = {};

    shortx8 ra0 = *(const shortx8*)(xb  + (size_t)(m0 + mA0) * HDIM + kg0 * 8);
    shortx8 ra1 = *(const shortx8*)(xb  + (size_t)(m0 + mA1) * HDIM + kg1 * 8);
    shortx8 rb0 = *(const shortx8*)(wxb + (size_t)(n0 + mA0) * HDIM + kg0 * 8);
    shortx8 rb1 = *(const shortx8*)(wxb + (size_t)(n0 + mA1) * HDIM + kg1 * 8);

    for (int kt = 0; kt < 64; ++kt) {
        ((shortx8*)As)[kg0 * 128 + mA0] = ra0;
        ((shortx8*)As)[kg1 * 128 + mA1] = ra1;
        ((shortx8*)Bs)[kg0 * 128 + mA0] = rb0;
        ((shortx8*)Bs)[kg1 * 128 + mA1] = rb1;
        __syncthreads();

        if (kt < 63) {
            int k = (kt + 1) * 32;
            ra0 = *(const shortx8*)(xb  + (size_t)(m0 + mA0) * HDIM + k + kg0 * 8);
            ra1 = *(const shortx8*)(xb  + (size_t)(m0 + mA1) * HDIM + k + kg1 * 8);
            rb0 = *(const shortx8*)(wxb + (size_t)(n0 + mA0) * HDIM + k + kg0 * 8);
            rb1 = *(const shortx8*)(wxb + (size_t)(n0 + mA1) * HDIM + k + kg1 * 8);
        }

        shortx8 af[4], bf[4];
#pragma unroll
        for (int mt = 0; mt < 4; ++mt)
            af[mt] = ((const shortx8*)As)[quad * 128 + wm + mt * 16 + l15];
#pragma unroll
        for (int nt = 0; nt < 4; ++nt)
            bf[nt] = ((const shortx8*)Bs)[quad * 128 + wn + nt * 16 + l15];
#pragma unroll
        for (int mt = 0; mt < 4; ++mt)
#pragma unroll
            for (int nt = 0; nt < 4; ++nt)
                acc[mt][nt] = __builtin_amdgcn_mfma_f32_16x16x32_bf16(af[mt], bf[nt], acc[mt][nt], 0, 0, 0);
        __syncthreads();
    }

#pragma unroll
    for (int nt = 0; nt < 4; ++nt) {
        int gn = n0 + wn + nt * 16 + l15;
        float bv = bias[gn];
#pragma unroll
        for (int mt = 0; mt < 4; ++mt) {
#pragma unroll
            for (int r = 0; r < 4; ++r) {
                int gm = m0 + wm + mt * 16 + quad * 4 + r;
                out[(size_t)gm * HDIM + gn] = acc[mt][nt][r] + bv;
            }
        }
    }
}

// ---------------- phase B: wave-autonomous persistent recurrence ----------------
// 128 WGs x 64 threads (1 wave). Rank r owns g-rows [16r, 16r+16), FULL K=2048:
// no cross-wave reduce, no __syncthreads anywhere in the step loop.
// Wh A-frags register-resident (64 x shortx8 = 256 VGPRs; __launch_bounds__(64,1)).
// h ring buffer (slot t = h_{t+1}) aliasing dead xb; producers store packed bf16
// via relaxed agent-scope stores (ack at coherent LLC), consumers use PLAIN
// cached b128 loads -- safe because every ring address is read-once (no stale
// L1/L2 line can exist) and flag-gated. Per-wave flags: rank publishes after an
// explicit s_waitcnt vmcnt(0) drain; consumers poll all 128 flags (2 per lane).
__global__ __launch_bounds__(64, 1) void rnn_scan_kernel(
    const __hip_bfloat16* __restrict__ whb,  // [2048][2048] Wh[g][k]
    __hip_bfloat16* __restrict__ ring,       // [512][32768] slots for h_1..h_512
    const __hip_bfloat16* __restrict__ h0,   // [32768] zeros (h_0)
    float* __restrict__ out,                 // d_out (u in -> h out, + tail h_last)
    unsigned* __restrict__ flags)            // [128][32] uint, 128B stride
{
    __shared__ float tru[16 * 17];   // u transpose (b,g)->(g,b), wave-local
    __shared__ float trs[16 * 20];   // result transpose (g,b)->(b,g), pad 20 for b128 align

    const int lane = threadIdx.x;
    const int quad = lane >> 4, l15 = lane & 15;
    const int rank = blockIdx.x;
    const int g0 = rank * 16;

    // preload A-frags: af[c] = A[m=l15][k=c*32+quad*8 .. +8)
    shortx8 af[64];
#pragma unroll
    for (int c = 0; c < 64; ++c)
        af[c] = *(const shortx8*)(whb + (size_t)(g0 + l15) * HDIM + c * 32 + quad * 8);

    const unsigned* fp0 = flags + lane * 32;
    const unsigned* fp1 = flags + (lane + 64) * 32;

    const int ob = lane >> 2, ogc = lane & 3;  // epilogue (b, g-chunk) mapping

    for (int t = 0; t < TLEN; ++t) {
        const __hip_bfloat16* hprev = (t == 0) ? h0 : (ring + (size_t)(t - 1) * 32768);
        __hip_bfloat16* hnext = ring + (size_t)t * 32768;

        // stage u tile: coalesced (b,g) loads -> LDS -> (g,b) registers.
        // All before the poll so it overlaps flag latency. Wave-local LDS
        // (single-wave WG): compiler's lgkmcnt orders write->read, no barrier.
        float uin[4], uv[4];
#pragma unroll
        for (int rr = 0; rr < 4; ++rr)
            uin[rr] = out[(size_t)(quad * 4 + rr) * TH + (size_t)t * HDIM + g0 + l15];
#pragma unroll
        for (int rr = 0; rr < 4; ++rr)
            tru[(quad * 4 + rr) * 17 + l15] = uin[rr];
#pragma unroll
        for (int rr = 0; rr < 4; ++rr)
            uv[rr] = tru[l15 * 17 + quad * 4 + rr];

        // poll all 128 producer flags (2 per lane)
        if (t > 0) {
            unsigned tgt = (unsigned)t;
            while (__hip_atomic_load(fp0, __ATOMIC_RELAXED, __HIP_MEMORY_SCOPE_AGENT) < tgt ||
                   __hip_atomic_load(fp1, __ATOMIC_RELAXED, __HIP_MEMORY_SCOPE_AGENT) < tgt) {}
        }
        __asm__ __volatile__("" ::: "memory");  // keep B loads below the poll

        // B loads (64 x contiguous-1KB wave segments) pipelined with 64 MFMAs,
        // 2 interleaved acc chains to break dependent-accumulate latency.
        floatx4 acc0 = {}, acc1 = {};
        shortx8 bfr[8];
#pragma unroll
        for (int c = 0; c < 8; ++c)
            bfr[c] = *(const shortx8*)(hprev + (size_t)(c * 4 + quad) * 128 + l15 * 8);
#pragma unroll
        for (int c = 0; c < 64; ++c) {
            shortx8 bv = bfr[c & 7];
            if (c < 56)
                bfr[c & 7] = *(const shortx8*)(hprev + (size_t)((c + 8) * 4 + quad) * 128 + l15 * 8);
            if (c & 1) acc1 = __builtin_amdgcn_mfma_f32_16x16x32_bf16(af[c], bv, acc1, 0, 0, 0);
            else       acc0 = __builtin_amdgcn_mfma_f32_16x16x32_bf16(af[c], bv, acc0, 0, 0, 0);
        }

        // s = acc + u  (layout: g_local = quad*4+rr, b = l15)
        float s[4];
#pragma unroll
        for (int rr = 0; rr < 4; ++rr) s[rr] = acc0[rr] + acc1[rr] + uv[rr];

        // ring store: 4 consecutive bf16 -> one packed 8B relaxed agent store
        __hip_bfloat16 hb0 = __float2bfloat16(s[0]);
        __hip_bfloat16 hb1 = __float2bfloat16(s[1]);
        __hip_bfloat16 hb2 = __float2bfloat16(s[2]);
        __hip_bfloat16 hb3 = __float2bfloat16(s[3]);
        unsigned lo = (unsigned)*(unsigned short*)&hb0 | ((unsigned)*(unsigned short*)&hb1 << 16);
        unsigned hi = (unsigned)*(unsigned short*)&hb2 | ((unsigned)*(unsigned short*)&hb3 << 16);
        ull pack = (ull)lo | ((ull)hi << 32);
        // elem idx for (g_abs = g0+quad*4+rr, b=l15) in layout (k>>3)*128+b*8+(k&7):
        int eidx = ((g0 >> 3) + (quad >> 1)) * 128 + l15 * 8 + (quad & 1) * 4;
        __hip_atomic_store((ull*)(hnext + eidx), pack, __ATOMIC_RELAXED, __HIP_MEMORY_SCOPE_AGENT);

        // transpose s -> (b,g), coalesced float4 out stores
#pragma unroll
        for (int rr = 0; rr < 4; ++rr)
            trs[l15 * 20 + quad * 4 + rr] = s[rr];
        floatx4 vo = *(const floatx4*)&trs[ob * 20 + ogc * 4];
        *(floatx4*)&out[(size_t)ob * TH + (size_t)t * HDIM + g0 + ogc * 4] = vo;
        if (t == TLEN - 1)
            *(floatx4*)&out[(size_t)OUT_MAIN + (size_t)ob * HDIM + g0 + ogc * 4] = vo;

        // drain all vmem stores (ring @LLC, out @L2), then publish this rank's flag
        __asm__ __volatile__("s_waitcnt vmcnt(0)" ::: "memory");
        if (lane == 0)
            __hip_atomic_store(flags + rank * 32, (unsigned)(t + 1),
                               __ATOMIC_RELAXED, __HIP_MEMORY_SCOPE_AGENT);
    }
}

// ---------------- launcher ----------------
extern "C" void kernel_launch(void* const* d_in, const int* in_sizes, int n_in,
                              void* d_out, int out_size, void* d_ws, size_t ws_size,
                              hipStream_t stream) {
    (void)in_sizes; (void)n_in; (void)out_size; (void)ws_size;
    const float* x    = (const float*)d_in[0];
    const float* W    = (const float*)d_in[1];
    const float* bias = (const float*)d_in[2];
    float* out = (float*)d_out;
    char* ws = (char*)d_ws;

    // ring (32 MB) ALIASES xb: xb is dead once gemm_u completes, before the scan.
    __hip_bfloat16* xb   = (__hip_bfloat16*)(ws);                      // 33,554,432 B
    __hip_bfloat16* ring = (__hip_bfloat16*)(ws);                      // 512 x 65,536 B
    __hip_bfloat16* wxb  = (__hip_bfloat16*)(ws + 33554432);           //  8,388,608 B
    __hip_bfloat16* whb  = (__hip_bfloat16*)(ws + 41943040);           //  8,388,608 B
    __hip_bfloat16* h0   = (__hip_bfloat16*)(ws + 50331648);           //     65,536 B
    unsigned* flags      = (unsigned*)(ws + 50331648 + 65536);         //     16,384 B

    // zero h_0 slot + flags (ws is re-poisoned before every launch)
    hipMemsetAsync(ws + 50331648, 0, 65536 + 16384, stream);

    cast_x_kernel<<<8192, 256, 0, stream>>>(x, xb, OUT_MAIN);
    cast_w_kernel<<<8192, 256, 0, stream>>>(W, wxb, whb);
    gemm_u_kernel<<<dim3(64, 16), 256, 0, stream>>>(xb, wxb, bias, out);
    rnn_scan_kernel<<<128, 64, 0, stream>>>(whb, ring, h0, out, flags);
}

// Round 7
// 1451.884 us; speedup vs baseline: 5.9181x; 5.9181x over previous
//
#include <hip/hip_runtime.h>
#include <hip/hip_bf16.h>
#include <stdint.h>

#define HDIM 2048
#define BATCH 16
#define TLEN 512
#define TH   1048576        // TLEN*HDIM
#define OUT_MAIN 16777216   // BATCH*TLEN*HDIM

using floatx4 = __attribute__((ext_vector_type(4))) float;
using shortx8 = __attribute__((ext_vector_type(8))) short;
typedef unsigned long long ull;

static __device__ __forceinline__ short bf16bits(float f) {
    __hip_bfloat16 h = __float2bfloat16(f);
    return *(short*)&h;
}

// ---------------- cast kernels ----------------
__global__ void cast_x_kernel(const float* __restrict__ x, __hip_bfloat16* __restrict__ xb, int n) {
    int i = blockIdx.x * blockDim.x + threadIdx.x;
    int stride = gridDim.x * blockDim.x;
    for (; i < n; i += stride) xb[i] = __float2bfloat16(x[i]);
}

__global__ void cast_w_kernel(const float* __restrict__ W,
                              __hip_bfloat16* __restrict__ wxb,
                              __hip_bfloat16* __restrict__ whb) {
    int i = blockIdx.x * blockDim.x + threadIdx.x;
    int stride = gridDim.x * blockDim.x;
    for (; i < HDIM * HDIM; i += stride) {
        int g = i >> 11, k = i & (HDIM - 1);
        wxb[i] = __float2bfloat16(W[g * (2 * HDIM) + k]);
        whb[i] = __float2bfloat16(W[g * (2 * HDIM) + HDIM + k]);
    }
}

// Transpose + hi/lo split (after gemm_u; outputs alias dead xb).
__global__ void transpose_wh_kernel(const float* __restrict__ W,
                                    __hip_bfloat16* __restrict__ whT_hi,
                                    __hip_bfloat16* __restrict__ whT_lo,
                                    __hip_bfloat16* __restrict__ whb_lo) {
    __shared__ float tile[32][33];
    int bx = blockIdx.x * 32, by = blockIdx.y * 32;
    int tx = threadIdx.x, ty = threadIdx.y;  // (32,8)
#pragma unroll
    for (int r = 0; r < 32; r += 8) {
        float v = W[(size_t)(by + ty + r) * (2 * HDIM) + HDIM + bx + tx];
        tile[ty + r][tx] = v;
        __hip_bfloat16 h = __float2bfloat16(v);
        whb_lo[(size_t)(by + ty + r) * HDIM + bx + tx] = __float2bfloat16(v - __bfloat162float(h));
    }
    __syncthreads();
#pragma unroll
    for (int r = 0; r < 32; r += 8) {
        float v = tile[tx][ty + r];
        __hip_bfloat16 h = __float2bfloat16(v);
        whT_hi[(size_t)(bx + ty + r) * HDIM + by + tx] = h;
        whT_lo[(size_t)(bx + ty + r) * HDIM + by + tx] = __float2bfloat16(v - __bfloat162float(h));
    }
}

// ---------------- phase A: u = x @ Wx^T + b -> out (fp32) + ub (bf16) ----------------
__global__ __launch_bounds__(256) void gemm_u_kernel(
    const __hip_bfloat16* __restrict__ xb,
    const __hip_bfloat16* __restrict__ wxb,
    const float* __restrict__ bias,
    float* __restrict__ out,
    __hip_bfloat16* __restrict__ ub)
{
    __shared__ __align__(16) __hip_bfloat16 As[4 * 128 * 8];
    __shared__ __align__(16) __hip_bfloat16 Bs[4 * 128 * 8];

    const int j = threadIdx.x;
    const int m0 = blockIdx.x * 128;
    const int n0 = blockIdx.y * 128;
    const int w = j >> 6, lane = j & 63;
    const int wm = (w >> 1) * 64, wn = (w & 1) * 64;
    const int quad = lane >> 4, l15 = lane & 15;

    const int mA0 = j & 127, kg0 = j >> 7;
    const int mA1 = (j + 256) & 127, kg1 = (j + 256) >> 7;

    floatx4 acc[4][4] = {};

    shortx8 ra0 = *(const shortx8*)(xb  + (size_t)(m0 + mA0) * HDIM + kg0 * 8);
    shortx8 ra1 = *(const shortx8*)(xb  + (size_t)(m0 + mA1) * HDIM + kg1 * 8);
    shortx8 rb0 = *(const shortx8*)(wxb + (size_t)(n0 + mA0) * HDIM + kg0 * 8);
    shortx8 rb1 = *(const shortx8*)(wxb + (size_t)(n0 + mA1) * HDIM + kg1 * 8);

    for (int kt = 0; kt < 64; ++kt) {
        ((shortx8*)As)[kg0 * 128 + mA0] = ra0;
        ((shortx8*)As)[kg1 * 128 + mA1] = ra1;
        ((shortx8*)Bs)[kg0 * 128 + mA0] = rb0;
        ((shortx8*)Bs)[kg1 * 128 + mA1] = rb1;
        __syncthreads();

        if (kt < 63) {
            int k = (kt + 1) * 32;
            ra0 = *(const shortx8*)(xb  + (size_t)(m0 + mA0) * HDIM + k + kg0 * 8);
            ra1 = *(const shortx8*)(xb  + (size_t)(m0 + mA1) * HDIM + k + kg1 * 8);
            rb0 = *(const shortx8*)(wxb + (size_t)(n0 + mA0) * HDIM + k + kg0 * 8);
            rb1 = *(const shortx8*)(wxb + (size_t)(n0 + mA1) * HDIM + k + kg1 * 8);
        }

        shortx8 af[4], bf[4];
#pragma unroll
        for (int mt = 0; mt < 4; ++mt)
            af[mt] = ((const shortx8*)As)[quad * 128 + wm + mt * 16 + l15];
#pragma unroll
        for (int nt = 0; nt < 4; ++nt)
            bf[nt] = ((const shortx8*)Bs)[quad * 128 + wn + nt * 16 + l15];
#pragma unroll
        for (int mt = 0; mt < 4; ++mt)
#pragma unroll
            for (int nt = 0; nt < 4; ++nt)
                acc[mt][nt] = __builtin_amdgcn_mfma_f32_16x16x32_bf16(af[mt], bf[nt], acc[mt][nt], 0, 0, 0);
        __syncthreads();
    }

#pragma unroll
    for (int nt = 0; nt < 4; ++nt) {
        int gn = n0 + wn + nt * 16 + l15;
        float bv = bias[gn];
#pragma unroll
        for (int mt = 0; mt < 4; ++mt) {
#pragma unroll
            for (int r = 0; r < 4; ++r) {
                int gm = m0 + wm + mt * 16 + quad * 4 + r;
                float v = acc[mt][nt][r] + bv;
                out[(size_t)gm * HDIM + gn] = v;
                ub[(size_t)gm * HDIM + gn] = __float2bfloat16(v);
            }
        }
    }
}

// ---------------- Wh2 = Wh*Wh, hi/lo factors in, hi/lo out ----------------
__global__ __launch_bounds__(256) void gemm_w2_kernel(
    const __hip_bfloat16* __restrict__ whh,
    const __hip_bfloat16* __restrict__ whl,
    const __hip_bfloat16* __restrict__ wtH,
    const __hip_bfloat16* __restrict__ wtL,
    __hip_bfloat16* __restrict__ w2h,
    __hip_bfloat16* __restrict__ w2l)
{
    __shared__ __align__(16) __hip_bfloat16 AsH[4 * 128 * 8];
    __shared__ __align__(16) __hip_bfloat16 AsL[4 * 128 * 8];
    __shared__ __align__(16) __hip_bfloat16 BsH[4 * 128 * 8];
    __shared__ __align__(16) __hip_bfloat16 BsL[4 * 128 * 8];

    const int j = threadIdx.x;
    const int m0 = blockIdx.x * 128;
    const int n0 = blockIdx.y * 128;
    const int w = j >> 6, lane = j & 63;
    const int wm = (w >> 1) * 64, wn = (w & 1) * 64;
    const int quad = lane >> 4, l15 = lane & 15;

    const int mA0 = j & 127, kg0 = j >> 7;
    const int mA1 = (j + 256) & 127, kg1 = (j + 256) >> 7;

    floatx4 acc[4][4] = {};

    shortx8 rah0 = *(const shortx8*)(whh + (size_t)(m0 + mA0) * HDIM + kg0 * 8);
    shortx8 rah1 = *(const shortx8*)(whh + (size_t)(m0 + mA1) * HDIM + kg1 * 8);
    shortx8 ral0 = *(const shortx8*)(whl + (size_t)(m0 + mA0) * HDIM + kg0 * 8);
    shortx8 ral1 = *(const shortx8*)(whl + (size_t)(m0 + mA1) * HDIM + kg1 * 8);
    shortx8 rbh0 = *(const shortx8*)(wtH + (size_t)(n0 + mA0) * HDIM + kg0 * 8);
    shortx8 rbh1 = *(const shortx8*)(wtH + (size_t)(n0 + mA1) * HDIM + kg1 * 8);
    shortx8 rbl0 = *(const shortx8*)(wtL + (size_t)(n0 + mA0) * HDIM + kg0 * 8);
    shortx8 rbl1 = *(const shortx8*)(wtL + (size_t)(n0 + mA1) * HDIM + kg1 * 8);

    for (int kt = 0; kt < 64; ++kt) {
        ((shortx8*)AsH)[kg0 * 128 + mA0] = rah0;
        ((shortx8*)AsH)[kg1 * 128 + mA1] = rah1;
        ((shortx8*)AsL)[kg0 * 128 + mA0] = ral0;
        ((shortx8*)AsL)[kg1 * 128 + mA1] = ral1;
        ((shortx8*)BsH)[kg0 * 128 + mA0] = rbh0;
        ((shortx8*)BsH)[kg1 * 128 + mA1] = rbh1;
        ((shortx8*)BsL)[kg0 * 128 + mA0] = rbl0;
        ((shortx8*)BsL)[kg1 * 128 + mA1] = rbl1;
        __syncthreads();

        if (kt < 63) {
            int k = (kt + 1) * 32;
            rah0 = *(const shortx8*)(whh + (size_t)(m0 + mA0) * HDIM + k + kg0 * 8);
            rah1 = *(const shortx8*)(whh + (size_t)(m0 + mA1) * HDIM + k + kg1 * 8);
            ral0 = *(const shortx8*)(whl + (size_t)(m0 + mA0) * HDIM + k + kg0 * 8);
            ral1 = *(const shortx8*)(whl + (size_t)(m0 + mA1) * HDIM + k + kg1 * 8);
            rbh0 = *(const shortx8*)(wtH + (size_t)(n0 + mA0) * HDIM + k + kg0 * 8);
            rbh1 = *(const shortx8*)(wtH + (size_t)(n0 + mA1) * HDIM + k + kg1 * 8);
            rbl0 = *(const shortx8*)(wtL + (size_t)(n0 + mA0) * HDIM + k + kg0 * 8);
            rbl1 = *(const shortx8*)(wtL + (size_t)(n0 + mA1) * HDIM + k + kg1 * 8);
        }

        shortx8 afh[4], afl[4], bfh[4], bfl[4];
#pragma unroll
        for (int mt = 0; mt < 4; ++mt) {
            afh[mt] = ((const shortx8*)AsH)[quad * 128 + wm + mt * 16 + l15];
            afl[mt] = ((const shortx8*)AsL)[quad * 128 + wm + mt * 16 + l15];
        }
#pragma unroll
        for (int nt = 0; nt < 4; ++nt) {
            bfh[nt] = ((const shortx8*)BsH)[quad * 128 + wn + nt * 16 + l15];
            bfl[nt] = ((const shortx8*)BsL)[quad * 128 + wn + nt * 16 + l15];
        }
#pragma unroll
        for (int mt = 0; mt < 4; ++mt)
#pragma unroll
            for (int nt = 0; nt < 4; ++nt) {
                acc[mt][nt] = __builtin_amdgcn_mfma_f32_16x16x32_bf16(afh[mt], bfh[nt], acc[mt][nt], 0, 0, 0);
                acc[mt][nt] = __builtin_amdgcn_mfma_f32_16x16x32_bf16(afh[mt], bfl[nt], acc[mt][nt], 0, 0, 0);
                acc[mt][nt] = __builtin_amdgcn_mfma_f32_16x16x32_bf16(afl[mt], bfh[nt], acc[mt][nt], 0, 0, 0);
            }
        __syncthreads();
    }

#pragma unroll
    for (int nt = 0; nt < 4; ++nt) {
        int gn = n0 + wn + nt * 16 + l15;
#pragma unroll
        for (int mt = 0; mt < 4; ++mt)
#pragma unroll
            for (int r = 0; r < 4; ++r) {
                int gm = m0 + wm + mt * 16 + quad * 4 + r;
                float a = acc[mt][nt][r];
                __hip_bfloat16 h = __float2bfloat16(a);
                w2h[(size_t)gm * HDIM + gn] = h;
                w2l[(size_t)gm * HDIM + gn] = __float2bfloat16(a - __bfloat162float(h));
            }
    }
}

// ---------------- v = u + Wh*u_shift (hi/lo Wh on B side; t==0 rows keep u) ----------------
__global__ __launch_bounds__(256) void gemm_v_kernel(
    const __hip_bfloat16* __restrict__ ub,
    const __hip_bfloat16* __restrict__ whb,
    const __hip_bfloat16* __restrict__ whl,
    float* __restrict__ out)
{
    __shared__ __align__(16) __hip_bfloat16 As[4 * 128 * 8];
    __shared__ __align__(16) __hip_bfloat16 BsH[4 * 128 * 8];
    __shared__ __align__(16) __hip_bfloat16 BsL[4 * 128 * 8];

    const int j = threadIdx.x;
    const int m0 = blockIdx.x * 128;
    const int n0 = blockIdx.y * 128;
    const int w = j >> 6, lane = j & 63;
    const int wm = (w >> 1) * 64, wn = (w & 1) * 64;
    const int quad = lane >> 4, l15 = lane & 15;

    const int mA0 = j & 127, kg0 = j >> 7;
    const int mA1 = (j + 256) & 127, kg1 = (j + 256) >> 7;

    int rowA0 = m0 + mA0 - 1; if (rowA0 < 0) rowA0 = 0;
    int rowA1 = m0 + mA1 - 1; if (rowA1 < 0) rowA1 = 0;

    floatx4 acc[4][4] = {};

    shortx8 ra0  = *(const shortx8*)(ub  + (size_t)rowA0 * HDIM + kg0 * 8);
    shortx8 ra1  = *(const shortx8*)(ub  + (size_t)rowA1 * HDIM + kg1 * 8);
    shortx8 rbh0 = *(const shortx8*)(whb + (size_t)(n0 + mA0) * HDIM + kg0 * 8);
    shortx8 rbh1 = *(const shortx8*)(whb + (size_t)(n0 + mA1) * HDIM + kg1 * 8);
    shortx8 rbl0 = *(const shortx8*)(whl + (size_t)(n0 + mA0) * HDIM + kg0 * 8);
    shortx8 rbl1 = *(const shortx8*)(whl + (size_t)(n0 + mA1) * HDIM + kg1 * 8);

    for (int kt = 0; kt < 64; ++kt) {
        ((shortx8*)As)[kg0 * 128 + mA0] = ra0;
        ((shortx8*)As)[kg1 * 128 + mA1] = ra1;
        ((shortx8*)BsH)[kg0 * 128 + mA0] = rbh0;
        ((shortx8*)BsH)[kg1 * 128 + mA1] = rbh1;
        ((shortx8*)BsL)[kg0 * 128 + mA0] = rbl0;
        ((shortx8*)BsL)[kg1 * 128 + mA1] = rbl1;
        __syncthreads();

        if (kt < 63) {
            int k = (kt + 1) * 32;
            ra0  = *(const shortx8*)(ub  + (size_t)rowA0 * HDIM + k + kg0 * 8);
            ra1  = *(const shortx8*)(ub  + (size_t)rowA1 * HDIM + k + kg1 * 8);
            rbh0 = *(const shortx8*)(whb + (size_t)(n0 + mA0) * HDIM + k + kg0 * 8);
            rbh1 = *(const shortx8*)(whb + (size_t)(n0 + mA1) * HDIM + k + kg1 * 8);
            rbl0 = *(const shortx8*)(whl + (size_t)(n0 + mA0) * HDIM + k + kg0 * 8);
            rbl1 = *(const shortx8*)(whl + (size_t)(n0 + mA1) * HDIM + k + kg1 * 8);
        }

        shortx8 af[4], bfh[4], bfl[4];
#pragma unroll
        for (int mt = 0; mt < 4; ++mt)
            af[mt] = ((const shortx8*)As)[quad * 128 + wm + mt * 16 + l15];
#pragma unroll
        for (int nt = 0; nt < 4; ++nt) {
            bfh[nt] = ((const shortx8*)BsH)[quad * 128 + wn + nt * 16 + l15];
            bfl[nt] = ((const shortx8*)BsL)[quad * 128 + wn + nt * 16 + l15];
        }
#pragma unroll
        for (int mt = 0; mt < 4; ++mt)
#pragma unroll
            for (int nt = 0; nt < 4; ++nt) {
                acc[mt][nt] = __builtin_amdgcn_mfma_f32_16x16x32_bf16(af[mt], bfh[nt], acc[mt][nt], 0, 0, 0);
                acc[mt][nt] = __builtin_amdgcn_mfma_f32_16x16x32_bf16(af[mt], bfl[nt], acc[mt][nt], 0, 0, 0);
            }
        __syncthreads();
    }

#pragma unroll
    for (int nt = 0; nt < 4; ++nt) {
        int gn = n0 + wn + nt * 16 + l15;
#pragma unroll
        for (int mt = 0; mt < 4; ++mt)
#pragma unroll
            for (int r = 0; r < 4; ++r) {
                int gm = m0 + wm + mt * 16 + quad * 4 + r;
                float uval = out[(size_t)gm * HDIM + gn];
                float res = ((gm & 511) == 0) ? uval : (acc[mt][nt][r] + uval);
                out[(size_t)gm * HDIM + gn] = res;
            }
    }
}

// ---------------- phase B: two parity chains, fp32 ring, hi/lo everywhere ----------------
// o_t = v_t + Wh2 * o_{t-2}. 128 WGs x 512 thr: chain=bid&1, rank=bid>>1.
// Ring stores o as FP32 (slot = s*2+chain, 128KB). Consumers load fp32 b128
// (coalesced, read-once, flag-gated plain loads) and split to bf16 hi/lo in
// registers; MFMA: Ah*Hh + Ah*Hl + Al*Hh (dropped Al*Hl ~1e-5 rel).
// out/tail stores issued AFTER the flag publication -- they retire during the
// next step's poll window instead of gating the inter-WG critical path.
__global__ __launch_bounds__(512) void rnn_scan_kernel(
    const __hip_bfloat16* __restrict__ w2h,
    const __hip_bfloat16* __restrict__ w2l,
    float* __restrict__ ring,                // [512][32768] fp32
    float* __restrict__ out,
    unsigned* __restrict__ flags)            // [2][64][32] uint, 128B stride
{
    __shared__ float ps[8 * 2 * 16 * 17];

    const int j = threadIdx.x;
    const int w = j >> 6, lane = j & 63;
    const int quad = lane >> 4, l15 = lane & 15;
    const int chain = blockIdx.x & 1;
    const int rank = blockIdx.x >> 1;
    const int n0 = rank * 32;

    unsigned* myflag = flags + (chain * 64 + rank) * 32;
    const unsigned* pollbase = flags + chain * 64 * 32;

    shortx8 afh[2][8], afl[2][8];
#pragma unroll
    for (int gt = 0; gt < 2; ++gt)
#pragma unroll
        for (int c = 0; c < 8; ++c) {
            int row = n0 + gt * 16 + l15;
            int k = w * 256 + c * 32 + quad * 8;
            afh[gt][c] = *(const shortx8*)(w2h + (size_t)row * HDIM + k);
            afl[gt][c] = *(const shortx8*)(w2l + (size_t)row * HDIM + k);
        }

    const int rn = j & 31, rb = j >> 5;
    const int gt_r = rn >> 4, row_r = rn & 15;

    for (int s = 0; s < 256; ++s) {
        const int t = chain + 2 * s;
        float* slot_next = ring + (size_t)(s * 2 + chain) * 32768;

        // prefetch v (overlaps poll latency)
        float uv = out[(size_t)rb * TH + (size_t)t * HDIM + n0 + rn];

        floatx4 acc[2][2] = {};
        if (s > 0) {
            const float* slot_prev = ring + (size_t)((s - 1) * 2 + chain) * 32768;
            // wave-local wait on this chain's 8 producers for wave w's K-slice
            if (lane < 8) {
                const unsigned* fp = pollbase + (w * 8 + lane) * 32;
                while (__hip_atomic_load(fp, __ATOMIC_RELAXED, __HIP_MEMORY_SCOPE_AGENT) < (unsigned)s) {}
            }
            __asm__ __volatile__("" ::: "memory");

#pragma unroll
            for (int c = 0; c < 8; ++c) {
                int kg = w * 32 + c * 4 + quad;
                floatx4 f0 = *(const floatx4*)(slot_prev + kg * 128 + l15 * 8);
                floatx4 f1 = *(const floatx4*)(slot_prev + kg * 128 + l15 * 8 + 4);
                shortx8 bh, bl;
#pragma unroll
                for (int e = 0; e < 4; ++e) {
                    __hip_bfloat16 h0 = __float2bfloat16(f0[e]);
                    bh[e] = *(short*)&h0;
                    __hip_bfloat16 l0 = __float2bfloat16(f0[e] - __bfloat162float(h0));
                    bl[e] = *(short*)&l0;
                    __hip_bfloat16 h1 = __float2bfloat16(f1[e]);
                    bh[4 + e] = *(short*)&h1;
                    __hip_bfloat16 l1 = __float2bfloat16(f1[e] - __bfloat162float(h1));
                    bl[4 + e] = *(short*)&l1;
                }
                int cp = c & 1;
                acc[0][cp] = __builtin_amdgcn_mfma_f32_16x16x32_bf16(afh[0][c], bh, acc[0][cp], 0, 0, 0);
                acc[0][cp] = __builtin_amdgcn_mfma_f32_16x16x32_bf16(afh[0][c], bl, acc[0][cp], 0, 0, 0);
                acc[0][cp] = __builtin_amdgcn_mfma_f32_16x16x32_bf16(afl[0][c], bh, acc[0][cp], 0, 0, 0);
                acc[1][cp] = __builtin_amdgcn_mfma_f32_16x16x32_bf16(afh[1][c], bh, acc[1][cp], 0, 0, 0);
                acc[1][cp] = __builtin_amdgcn_mfma_f32_16x16x32_bf16(afh[1][c], bl, acc[1][cp], 0, 0, 0);
                acc[1][cp] = __builtin_amdgcn_mfma_f32_16x16x32_bf16(afl[1][c], bh, acc[1][cp], 0, 0, 0);
            }
        }

        floatx4 a0 = acc[0][0] + acc[0][1];
        floatx4 a1 = acc[1][0] + acc[1][1];
#pragma unroll
        for (int r = 0; r < 4; ++r) {
            ps[((w * 2 + 0) * 16 + quad * 4 + r) * 17 + l15] = a0[r];
            ps[((w * 2 + 1) * 16 + quad * 4 + r) * 17 + l15] = a1[r];
        }
        __syncthreads();

        float sv_f = uv;
#pragma unroll
        for (int ww = 0; ww < 8; ++ww)
            sv_f += ps[((ww * 2 + gt_r) * 16 + row_r) * 17 + rb];

        int n = n0 + rn;

        // fp32 ring store: pack (n, n+1) into one 8B relaxed agent store
        unsigned bits = __float_as_uint(sv_f);
        unsigned obits = __shfl_down(bits, 1);
        if ((j & 1) == 0) {
            ull pk = (ull)bits | ((ull)obits << 32);
            int idx = (n >> 3) * 128 + rb * 8 + (n & 7);  // n even -> 8B aligned
            __hip_atomic_store((ull*)(slot_next + idx), pk, __ATOMIC_RELAXED, __HIP_MEMORY_SCOPE_AGENT);
        }

        // barrier drains ring stores (vmcnt(0) before s_barrier), then publish
        __syncthreads();
        if (j == 0)
            __hip_atomic_store(myflag, (unsigned)(s + 1), __ATOMIC_RELAXED, __HIP_MEMORY_SCOPE_AGENT);

        // out stores AFTER the flag: off the inter-WG critical path
        out[(size_t)rb * TH + (size_t)t * HDIM + n] = sv_f;
        if (t == TLEN - 1) out[(size_t)OUT_MAIN + (size_t)rb * HDIM + n] = sv_f;
    }
}

// ---------------- launcher ----------------
extern "C" void kernel_launch(void* const* d_in, const int* in_sizes, int n_in,
                              void* d_out, int out_size, void* d_ws, size_t ws_size,
                              hipStream_t stream) {
    (void)in_sizes; (void)n_in; (void)out_size; (void)ws_size;
    const float* x    = (const float*)d_in[0];
    const float* W    = (const float*)d_in[1];
    const float* bias = (const float*)d_in[2];
    float* out = (float*)d_out;
    char* ws = (char*)d_ws;

    // Memory plan (84.0 MB total; ws proven >= 92.4 MB in rounds 5/6):
    //  [0,64M): ring fp32 (scan only). Aliases, all dead before scan:
    //     xb [0,32M) (dead after gemm_u); whT_hi [0,8M)+whT_lo [8,16M)+whb_lo [16,24M)
    //     (transpose -> gemm_v/gemm_w2); wxb [32,40M) (dead after gemm_u);
    //     whb [40,48M) (dead after gemm_w2); ub [48,80M) lower half (dead after gemm_v).
    //  [64,72M): wh2_hi, [72,80M): wh2_lo -- written by gemm_w2 AFTER gemm_v (ub dead).
    //  [80M,+16K): flags.
    __hip_bfloat16* xb     = (__hip_bfloat16*)(ws);
    __hip_bfloat16* whT_hi = (__hip_bfloat16*)(ws);
    __hip_bfloat16* whT_lo = (__hip_bfloat16*)(ws + 8388608);
    __hip_bfloat16* whb_lo = (__hip_bfloat16*)(ws + 16777216);
    float*          ring   = (float*)(ws);
    __hip_bfloat16* wxb    = (__hip_bfloat16*)(ws + 33554432);
    __hip_bfloat16* whb    = (__hip_bfloat16*)(ws + 41943040);
    __hip_bfloat16* ub     = (__hip_bfloat16*)(ws + 50331648);
    __hip_bfloat16* wh2_hi = (__hip_bfloat16*)(ws + 67108864);
    __hip_bfloat16* wh2_lo = (__hip_bfloat16*)(ws + 75497472);
    unsigned* flags        = (unsigned*)(ws + 83886080);

    hipMemsetAsync(ws + 83886080, 0, 16384, stream);

    cast_x_kernel<<<8192, 256, 0, stream>>>(x, xb, OUT_MAIN);
    cast_w_kernel<<<8192, 256, 0, stream>>>(W, wxb, whb);
    gemm_u_kernel<<<dim3(64, 16), 256, 0, stream>>>(xb, wxb, bias, out, ub);
    transpose_wh_kernel<<<dim3(64, 64), dim3(32, 8), 0, stream>>>(W, whT_hi, whT_lo, whb_lo);
    gemm_v_kernel<<<dim3(64, 16), 256, 0, stream>>>(ub, whb, whb_lo, out);
    gemm_w2_kernel<<<dim3(16, 16), 256, 0, stream>>>(whb, whb_lo, whT_hi, whT_lo, wh2_hi, wh2_lo);
    rnn_scan_kernel<<<128, 512, 0, stream>>>(wh2_hi, wh2_lo, ring, out, flags);
}